// Round 2
// baseline (1664.120 us; speedup 1.0000x reference)
//
#include <hip/hip_runtime.h>
#include <cstdint>
#include <cstddef>

typedef unsigned short u16;
typedef short short8 __attribute__((ext_vector_type(8)));
typedef float floatx4 __attribute__((ext_vector_type(4)));

#define DEVI __device__ __forceinline__

static constexpr int B_ = 2, S_ = 2048, M_ = 1024, H_ = 16, E_ = 8, DFF_ = 4096;
static constexpr int T_ = B_ * S_;          // 4096 tokens
static constexpr int QKVN = 3 * M_;         // 3072

// ---------- scalar bf16 helpers ----------
DEVI float bf2f(u16 u) { union { unsigned u; float f; } v; v.u = ((unsigned)u) << 16; return v.f; }
DEVI u16 f2bf(float f) {
  union { float f; unsigned u; } v; v.f = f;
  unsigned r = (v.u + 0x7FFF + ((v.u >> 16) & 1)) >> 16;   // RNE
  return (u16)r;
}

// ---------- async global->LDS 16B (wave-uniform base + lane*16 layout) ----------
DEVI void gload_lds16(const void* g, void* l) {
  __builtin_amdgcn_global_load_lds(
      (const __attribute__((address_space(1))) unsigned int*)(uintptr_t)g,
      (__attribute__((address_space(3))) unsigned int*)(unsigned int)(uintptr_t)l,
      16, 0, 0);
}

// ---------- fp32 -> bf16 bulk cast ----------
__global__ __launch_bounds__(256) void cast_bf16_kernel(const float* __restrict__ src,
                                                        u16* __restrict__ dst, int n4) {
  int i = blockIdx.x * 256 + threadIdx.x;
  int stride = gridDim.x * 256;
  for (; i < n4; i += stride) {
    float4 v = ((const float4*)src)[i];
    ushort4 o;
    o.x = f2bf(v.x); o.y = f2bf(v.y); o.z = f2bf(v.z); o.w = f2bf(v.w);
    ((ushort4*)dst)[i] = o;
  }
}

// ---------- LayerNorm (block per token, M=1024, 4 elems/thread) ----------
__global__ __launch_bounds__(256) void ln_kernel(const float* __restrict__ x,
                                                 const float* __restrict__ g,
                                                 const float* __restrict__ b,
                                                 u16* __restrict__ out) {
  int t = blockIdx.x;
  int tid = threadIdx.x;
  float4 v = ((const float4*)(x + (size_t)t * M_))[tid];
  float s = v.x + v.y + v.z + v.w;
  float sq = v.x * v.x + v.y * v.y + v.z * v.z + v.w * v.w;
  for (int m = 1; m < 64; m <<= 1) { s += __shfl_xor(s, m); sq += __shfl_xor(sq, m); }
  __shared__ float ps[4], pq[4];
  int w = tid >> 6;
  if ((tid & 63) == 0) { ps[w] = s; pq[w] = sq; }
  __syncthreads();
  s = ps[0] + ps[1] + ps[2] + ps[3];
  sq = pq[0] + pq[1] + pq[2] + pq[3];
  float mean = s * (1.f / M_);
  float var = sq * (1.f / M_) - mean * mean;
  float rstd = rsqrtf(var + 1e-5f);
  int c = tid * 4;
  ushort4 o;
  o.x = f2bf((v.x - mean) * rstd * g[c + 0] + b[c + 0]);
  o.y = f2bf((v.y - mean) * rstd * g[c + 1] + b[c + 1]);
  o.z = f2bf((v.z - mean) * rstd * g[c + 2] + b[c + 2]);
  o.w = f2bf((v.w - mean) * rstd * g[c + 3] + b[c + 3]);
  ((ushort4*)(out + (size_t)t * M_))[tid] = o;
}

// =================================================================
// Core GEMM: C[rows x N] = A[rows x K](bf16) @ W[N x K]^T(bf16)
// 128x128 tile, BK=32, 256 thr = 4 waves (2x2 of 64x64), 16x16x32 MFMA.
// LDS chunk swizzle: stored slot = kchunk ^ ((row>>1)&3)  (2-way free).
// EPI: 0 = bf16 out + bias; 1 = f32 out + bias + residual; 2 = f32 out.
// =================================================================
template <int EPI>
__global__ __launch_bounds__(256, 2) void gemm_bt_kernel(
    const u16* __restrict__ A, int lda,
    const u16* __restrict__ Wb, long wstride, int ldw, int K,
    const float* __restrict__ bias, const float* __restrict__ resid, int ldr,
    void* __restrict__ Cout, int ldc,
    const int* __restrict__ d_off, const int* __restrict__ d_cnt, int rowsDefault) {
  int e = blockIdx.z;
  const u16* W = Wb + (long)e * wstride;
  int rowBase = 0, rows = rowsDefault;
  if (d_off) { rowBase = d_off[e]; rows = d_cnt[e]; }
  int mt0 = blockIdx.x * 128;
  if (mt0 >= rows) return;
  int col0 = blockIdx.y * 128;

  __shared__ u16 As[128 * 32];
  __shared__ u16 Bs[128 * 32];
  char* AsB = (char*)As;
  char* BsB = (char*)Bs;

  int tid = threadIdx.x;
  int lane = tid & 63, wave = tid >> 6;
  int quad = lane >> 4, nlo = lane & 15;
  int wr = wave >> 1, wc = wave & 1;

  int r0 = tid >> 2, r1 = (tid + 256) >> 2;
  int slot = tid & 3;
  int kc0 = slot ^ ((r0 >> 1) & 3);
  int kc1 = slot ^ ((r1 >> 1) & 3);
  int ar0 = rowBase + mt0 + r0; if (ar0 >= rowBase + rows) ar0 = rowBase;
  int ar1 = rowBase + mt0 + r1; if (ar1 >= rowBase + rows) ar1 = rowBase;
  const u16* Ap0 = A + (size_t)ar0 * lda + kc0 * 8;
  const u16* Ap1 = A + (size_t)ar1 * lda + kc1 * 8;
  const u16* Wp0 = W + (size_t)(col0 + r0) * ldw + kc0 * 8;
  const u16* Wp1 = W + (size_t)(col0 + r1) * ldw + kc1 * 8;
  char* a_dst0 = AsB + tid * 16;
  char* a_dst1 = AsB + (tid + 256) * 16;
  char* b_dst0 = BsB + tid * 16;
  char* b_dst1 = BsB + (tid + 256) * 16;

  floatx4 acc[4][4];
#pragma unroll
  for (int i = 0; i < 4; i++)
#pragma unroll
    for (int j = 0; j < 4; j++) acc[i][j] = (floatx4)0.f;

  for (int k0 = 0; k0 < K; k0 += 32) {
    __syncthreads();
    gload_lds16(Ap0 + k0, a_dst0);
    gload_lds16(Ap1 + k0, a_dst1);
    gload_lds16(Wp0 + k0, b_dst0);
    gload_lds16(Wp1 + k0, b_dst1);
    __syncthreads();
    short8 af[4], bfv[4];
#pragma unroll
    for (int mt = 0; mt < 4; mt++) {
      int rr = wr * 64 + mt * 16 + nlo;
      int ch = rr * 4 + (quad ^ ((rr >> 1) & 3));
      af[mt] = *(const short8*)(AsB + ch * 16);
    }
#pragma unroll
    for (int nt = 0; nt < 4; nt++) {
      int rr = wc * 64 + nt * 16 + nlo;
      int ch = rr * 4 + (quad ^ ((rr >> 1) & 3));
      bfv[nt] = *(const short8*)(BsB + ch * 16);
    }
#pragma unroll
    for (int mt = 0; mt < 4; mt++)
#pragma unroll
      for (int nt = 0; nt < 4; nt++)
        acc[mt][nt] = __builtin_amdgcn_mfma_f32_16x16x32_bf16(af[mt], bfv[nt], acc[mt][nt], 0, 0, 0);
  }

#pragma unroll
  for (int mt = 0; mt < 4; mt++) {
#pragma unroll
    for (int r = 0; r < 4; r++) {
      int row = rowBase + mt0 + wr * 64 + mt * 16 + quad * 4 + r;
      if (row >= rowBase + rows) continue;
#pragma unroll
      for (int nt = 0; nt < 4; nt++) {
        int col = col0 + wc * 64 + nt * 16 + nlo;
        float v = acc[mt][nt][r];
        if (EPI == 0) {
          v += bias[col];
          ((u16*)Cout)[(size_t)row * ldc + col] = f2bf(v);
        } else if (EPI == 1) {
          v += bias[col] + resid[(size_t)row * ldr + col];
          ((float*)Cout)[(size_t)row * ldc + col] = v;
        } else {
          ((float*)Cout)[(size_t)row * ldc + col] = v;
        }
      }
    }
  }
}

// =================================================================
// Fused MoE w1/w3 GEMM with token gather + SwiGLU epilogue -> g (bf16)
// =================================================================
__global__ __launch_bounds__(256, 2) void gemm_moe13_kernel(
    const u16* __restrict__ h2, const u16* __restrict__ w1b, const u16* __restrict__ w3b,
    const int* __restrict__ d_off, const int* __restrict__ d_cnt,
    const int* __restrict__ tok_of, u16* __restrict__ g) {
  int e = blockIdx.z;
  int off = d_off[e], cnt = d_cnt[e];
  int mt0 = blockIdx.x * 128;
  if (mt0 >= cnt) return;
  int col0 = blockIdx.y * 128;
  const u16* W1 = w1b + (size_t)e * DFF_ * M_;
  const u16* W3 = w3b + (size_t)e * DFF_ * M_;

  __shared__ u16 As[128 * 32];
  __shared__ u16 B1s[128 * 32];
  __shared__ u16 B3s[128 * 32];
  char* AsB = (char*)As;
  char* B1B = (char*)B1s;
  char* B3B = (char*)B3s;

  int tid = threadIdx.x;
  int lane = tid & 63, wave = tid >> 6;
  int quad = lane >> 4, nlo = lane & 15;
  int wr = wave >> 1, wc = wave & 1;

  int r0 = tid >> 2, r1 = (tid + 256) >> 2;
  int slot = tid & 3;
  int kc0 = slot ^ ((r0 >> 1) & 3);
  int kc1 = slot ^ ((r1 >> 1) & 3);
  int a0 = off + mt0 + r0; if (a0 >= off + cnt) a0 = off;
  int a1 = off + mt0 + r1; if (a1 >= off + cnt) a1 = off;
  int tok0 = tok_of[a0], tok1 = tok_of[a1];
  const u16* Ap0 = h2 + (size_t)tok0 * M_ + kc0 * 8;
  const u16* Ap1 = h2 + (size_t)tok1 * M_ + kc1 * 8;
  const u16* W1p0 = W1 + (size_t)(col0 + r0) * M_ + kc0 * 8;
  const u16* W1p1 = W1 + (size_t)(col0 + r1) * M_ + kc1 * 8;
  const u16* W3p0 = W3 + (size_t)(col0 + r0) * M_ + kc0 * 8;
  const u16* W3p1 = W3 + (size_t)(col0 + r1) * M_ + kc1 * 8;

  floatx4 acc1[4][4], acc3[4][4];
#pragma unroll
  for (int i = 0; i < 4; i++)
#pragma unroll
    for (int j = 0; j < 4; j++) { acc1[i][j] = (floatx4)0.f; acc3[i][j] = (floatx4)0.f; }

  for (int k0 = 0; k0 < M_; k0 += 32) {
    __syncthreads();
    gload_lds16(Ap0 + k0, AsB + tid * 16);
    gload_lds16(Ap1 + k0, AsB + (tid + 256) * 16);
    gload_lds16(W1p0 + k0, B1B + tid * 16);
    gload_lds16(W1p1 + k0, B1B + (tid + 256) * 16);
    gload_lds16(W3p0 + k0, B3B + tid * 16);
    gload_lds16(W3p1 + k0, B3B + (tid + 256) * 16);
    __syncthreads();
    short8 af[4], b1f[4], b3f[4];
#pragma unroll
    for (int mt = 0; mt < 4; mt++) {
      int rr = wr * 64 + mt * 16 + nlo;
      int ch = rr * 4 + (quad ^ ((rr >> 1) & 3));
      af[mt] = *(const short8*)(AsB + ch * 16);
    }
#pragma unroll
    for (int nt = 0; nt < 4; nt++) {
      int rr = wc * 64 + nt * 16 + nlo;
      int ch = rr * 4 + (quad ^ ((rr >> 1) & 3));
      b1f[nt] = *(const short8*)(B1B + ch * 16);
      b3f[nt] = *(const short8*)(B3B + ch * 16);
    }
#pragma unroll
    for (int mt = 0; mt < 4; mt++)
#pragma unroll
      for (int nt = 0; nt < 4; nt++) {
        acc1[mt][nt] = __builtin_amdgcn_mfma_f32_16x16x32_bf16(af[mt], b1f[nt], acc1[mt][nt], 0, 0, 0);
        acc3[mt][nt] = __builtin_amdgcn_mfma_f32_16x16x32_bf16(af[mt], b3f[nt], acc3[mt][nt], 0, 0, 0);
      }
  }

#pragma unroll
  for (int mt = 0; mt < 4; mt++) {
#pragma unroll
    for (int r = 0; r < 4; r++) {
      int a = off + mt0 + wr * 64 + mt * 16 + quad * 4 + r;
      if (a >= off + cnt) continue;
#pragma unroll
      for (int nt = 0; nt < 4; nt++) {
        int col = col0 + wc * 64 + nt * 16 + nlo;
        float x1 = acc1[mt][nt][r];
        float x3 = acc3[mt][nt][r];
        float sil = x1 / (1.f + __expf(-x1));
        g[(size_t)a * DFF_ + col] = f2bf(sil * x3);
      }
    }
  }
}

// =================================================================
// Flash attention: block = (qblock of 64 rows, b*h); wave = 16 q rows.
// =================================================================
__global__ __launch_bounds__(256, 4) void attn_kernel(const u16* __restrict__ qkv,
                                                      u16* __restrict__ ctx) {
  int qblk = blockIdx.x;
  int bh = blockIdx.y;
  int b = bh >> 4, h = bh & 15;
  int tid = threadIdx.x;
  int wave = tid >> 6, lane = tid & 63;
  int quad = lane >> 4, nlo = lane & 15;
  int qw = qblk * 64 + wave * 16;

  __shared__ u16 Kl[32 * 72];
  __shared__ u16 Vl[64 * 56];
  __shared__ u16 Pl[4 * 16 * 56];
  u16* Pw = Pl + wave * 16 * 56;

  const size_t rs = 3072;
  const u16* base = qkv + (size_t)b * S_ * rs;

  short8 aq[2];
  {
    int qrow = qw + nlo;
    const u16* qp = base + (size_t)qrow * rs + h * 64 + quad * 8;
    aq[0] = *(const short8*)(qp);
    aq[1] = *(const short8*)(qp + 32);
  }

  floatx4 oc[4];
#pragma unroll
  for (int i = 0; i < 4; i++) oc[i] = (floatx4)0.f;
  float m_i[4], l_i[4];
#pragma unroll
  for (int r = 0; r < 4; r++) { m_i[r] = -1e30f; l_i[r] = 0.f; }

  int nkt = (qblk * 64) / 32 + 2;
  for (int kt = 0; kt < nkt; kt++) {
    int kbase = kt * 32;
    __syncthreads();
    {
      int key = tid >> 3, d0 = (tid & 7) * 8;
      const u16* kp = base + (size_t)(kbase + key) * rs + 1024 + h * 64 + d0;
      short8 kv = *(const short8*)kp;
      *(short8*)(Kl + key * 72 + d0) = kv;
      union { short8 v; u16 u[8]; } vv;
      vv.v = *(const short8*)(kp + 1024);
#pragma unroll
      for (int i = 0; i < 8; i++) Vl[(d0 + i) * 56 + key] = vv.u[i];
    }
    __syncthreads();
    if (kbase > qw + 15) continue;

    floatx4 sc[2];
    sc[0] = (floatx4)0.f; sc[1] = (floatx4)0.f;
#pragma unroll
    for (int nt = 0; nt < 2; nt++)
#pragma unroll
      for (int kd = 0; kd < 2; kd++) {
        short8 bk = *(const short8*)(Kl + (nt * 16 + nlo) * 72 + kd * 32 + quad * 8);
        sc[nt] = __builtin_amdgcn_mfma_f32_16x16x32_bf16(aq[kd], bk, sc[nt], 0, 0, 0);
      }

    float p[2][4], alpha[4];
#pragma unroll
    for (int r = 0; r < 4; r++) {
      int qrow = qw + quad * 4 + r;
      float s0v = sc[0][r]; if (kbase + nlo > qrow) s0v = -1e30f;
      float s1v = sc[1][r]; if (kbase + 16 + nlo > qrow) s1v = -1e30f;
      float mx = fmaxf(s0v, s1v);
#pragma unroll
      for (int m = 1; m < 16; m <<= 1) mx = fmaxf(mx, __shfl_xor(mx, m));
      float mnew = fmaxf(m_i[r], mx);
      alpha[r] = __expf(m_i[r] - mnew);
      float p0 = __expf(s0v - mnew), p1 = __expf(s1v - mnew);
      float rsum = p0 + p1;
#pragma unroll
      for (int m = 1; m < 16; m <<= 1) rsum += __shfl_xor(rsum, m);
      l_i[r] = l_i[r] * alpha[r] + rsum;
      m_i[r] = mnew;
      p[0][r] = p0; p[1][r] = p1;
    }
#pragma unroll
    for (int d = 0; d < 4; d++)
#pragma unroll
      for (int r = 0; r < 4; r++) oc[d][r] *= alpha[r];
#pragma unroll
    for (int nt = 0; nt < 2; nt++)
#pragma unroll
      for (int r = 0; r < 4; r++)
        Pw[(quad * 4 + r) * 56 + nt * 16 + nlo] = f2bf(p[nt][r]);

    short8 ap = *(const short8*)(Pw + nlo * 56 + quad * 8);
#pragma unroll
    for (int d = 0; d < 4; d++) {
      short8 bv = *(const short8*)(Vl + (d * 16 + nlo) * 56 + quad * 8);
      oc[d] = __builtin_amdgcn_mfma_f32_16x16x32_bf16(ap, bv, oc[d], 0, 0, 0);
    }
  }

  float inv[4];
#pragma unroll
  for (int r = 0; r < 4; r++) inv[r] = 1.f / l_i[r];
#pragma unroll
  for (int d = 0; d < 4; d++)
#pragma unroll
    for (int r = 0; r < 4; r++) {
      int qrow = qw + quad * 4 + r;
      ctx[((size_t)(b * S_ + qrow)) * M_ + h * 64 + d * 16 + nlo] = f2bf(oc[d][r] * inv[r]);
    }
}

// ---------- MoE routing: fp32 LN2 fused + double-accum gate logits ----------
// wave per token, 4 waves/block. Reads fp32 y directly (NOT bf16 h2) so the
// discrete top-2 selection matches the fp32 reference (bf16 logit noise was
// flipping the 2nd expert on ~1% of tokens -> absmax 0.72).
__global__ __launch_bounds__(256) void route_kernel(const float* __restrict__ y,
                                                    const float* __restrict__ g,
                                                    const float* __restrict__ b,
                                                    const float* __restrict__ gw,
                                                    float* __restrict__ topw,
                                                    int* __restrict__ topi) {
  int wave = threadIdx.x >> 6, lane = threadIdx.x & 63;
  int t = blockIdx.x * 4 + wave;
  const float* yr = y + (size_t)t * M_;
  float4 v[4];
  float s = 0.f, sq = 0.f;
#pragma unroll
  for (int i = 0; i < 4; i++) {
    v[i] = ((const float4*)yr)[lane + i * 64];
    s += v[i].x + v[i].y + v[i].z + v[i].w;
    sq += v[i].x * v[i].x + v[i].y * v[i].y + v[i].z * v[i].z + v[i].w * v[i].w;
  }
#pragma unroll
  for (int m = 1; m < 64; m <<= 1) { s += __shfl_xor(s, m); sq += __shfl_xor(sq, m); }
  float mean = s * (1.f / M_);
  float var = sq * (1.f / M_) - mean * mean;
  float rstd = rsqrtf(var + 1e-5f);

  double acc[8];
#pragma unroll
  for (int e = 0; e < 8; e++) acc[e] = 0.0;
#pragma unroll
  for (int i = 0; i < 4; i++) {
    int d = (lane + i * 64) * 4;
    float4 gg = ((const float4*)(g + d))[0];
    float4 bb = ((const float4*)(b + d))[0];
    float h0 = (v[i].x - mean) * rstd * gg.x + bb.x;
    float h1 = (v[i].y - mean) * rstd * gg.y + bb.y;
    float h2v = (v[i].z - mean) * rstd * gg.z + bb.z;
    float h3 = (v[i].w - mean) * rstd * gg.w + bb.w;
#pragma unroll
    for (int e = 0; e < 8; e++) {
      float4 w4 = ((const float4*)(gw + (size_t)e * M_ + d))[0];
      acc[e] += (double)h0 * w4.x + (double)h1 * w4.y + (double)h2v * w4.z + (double)h3 * w4.w;
    }
  }
#pragma unroll
  for (int e = 0; e < 8; e++)
#pragma unroll
    for (int m = 1; m < 64; m <<= 1) acc[e] += __shfl_xor(acc[e], m);
  if (lane == 0) {
    int i1 = 0; double v1 = acc[0];
#pragma unroll
    for (int e = 1; e < 8; e++) if (acc[e] > v1) { v1 = acc[e]; i1 = e; }
    int i2 = -1; double v2 = -1e300;
#pragma unroll
    for (int e = 0; e < 8; e++) if (e != i1 && acc[e] > v2) { v2 = acc[e]; i2 = e; }
    double z = exp(v2 - v1);
    topi[t * 2] = i1; topi[t * 2 + 1] = i2;
    topw[t * 2] = (float)(1.0 / (1.0 + z));
    topw[t * 2 + 1] = (float)(z / (1.0 + z));
  }
}

__global__ void zero_cnt_kernel(int* cnt) { if (threadIdx.x < 16) cnt[threadIdx.x] = 0; }

__global__ __launch_bounds__(256) void count_kernel(const int* __restrict__ topi, int* cnt) {
  int t = blockIdx.x * 256 + threadIdx.x;
  if (t < T_) {
    atomicAdd(&cnt[topi[2 * t]], 1);
    atomicAdd(&cnt[topi[2 * t + 1]], 1);
  }
}

__global__ void scan_kernel(const int* __restrict__ cnt, int* off) {
  if (threadIdx.x == 0) {
    int s = 0;
    for (int e = 0; e < E_; e++) { off[e] = s; s += cnt[e]; }
  }
}

__global__ __launch_bounds__(256) void assign_kernel(const int* __restrict__ topi,
                                                     const int* __restrict__ off, int* fill,
                                                     int* __restrict__ tok_of,
                                                     int* __restrict__ slot_of) {
  int t = blockIdx.x * 256 + threadIdx.x;
  if (t < T_) {
#pragma unroll
    for (int j = 0; j < 2; j++) {
      int e = topi[2 * t + j];
      int pos = atomicAdd(&fill[e], 1);
      int a = off[e] + pos;
      tok_of[a] = t;
      slot_of[2 * t + j] = a;
    }
  }
}

// ---------- final combine ----------
__global__ __launch_bounds__(256) void combine_kernel(const float* __restrict__ y,
                                                      const float* __restrict__ contrib,
                                                      const float* __restrict__ topw,
                                                      const int* __restrict__ slot_of,
                                                      float* __restrict__ out) {
  int t = blockIdx.x;
  int c = threadIdx.x;
  int s0 = slot_of[2 * t], s1 = slot_of[2 * t + 1];
  float w0 = topw[2 * t], w1 = topw[2 * t + 1];
  float4 a = ((const float4*)(y + (size_t)t * M_))[c];
  float4 p = ((const float4*)(contrib + (size_t)s0 * M_))[c];
  float4 q = ((const float4*)(contrib + (size_t)s1 * M_))[c];
  float4 o;
  o.x = a.x + w0 * p.x + w1 * q.x;
  o.y = a.y + w0 * p.y + w1 * q.y;
  o.z = a.z + w0 * p.z + w1 * q.z;
  o.w = a.w + w0 * p.w + w1 * q.w;
  ((float4*)(out + (size_t)t * M_))[c] = o;
}

// =================================================================
extern "C" void kernel_launch(void* const* d_in, const int* in_sizes, int n_in,
                              void* d_out, int out_size, void* d_ws, size_t ws_size,
                              hipStream_t stream) {
  const float* x = (const float*)d_in[0];
  const float* ln1g = (const float*)d_in[1];
  const float* ln1b = (const float*)d_in[2];
  const float* qkvw = (const float*)d_in[3];
  const float* qkvb = (const float*)d_in[4];
  const float* ow = (const float*)d_in[5];
  const float* ob = (const float*)d_in[6];
  const float* ln2g = (const float*)d_in[7];
  const float* ln2b = (const float*)d_in[8];
  const float* gatew = (const float*)d_in[9];
  const float* w1 = (const float*)d_in[10];
  const float* w2 = (const float*)d_in[11];
  const float* w3 = (const float*)d_in[12];
  float* out = (float*)d_out;

  char* p = (char*)d_ws;
  auto alloc = [&](size_t bytes) {
    char* r = p;
    p += (bytes + 255) & ~(size_t)255;
    return r;
  };
  u16* wqb = (u16*)alloc((size_t)QKVN * M_ * 2);
  u16* wob = (u16*)alloc((size_t)M_ * M_ * 2);
  u16* w1b = (u16*)alloc((size_t)E_ * DFF_ * M_ * 2);
  u16* w2b = (u16*)alloc((size_t)E_ * M_ * DFF_ * 2);
  u16* w3b = (u16*)alloc((size_t)E_ * DFF_ * M_ * 2);
  u16* hbuf = (u16*)alloc((size_t)T_ * M_ * 2);
  u16* qkvb16 = (u16*)alloc((size_t)T_ * QKVN * 2);
  u16* ctx = (u16*)alloc((size_t)T_ * M_ * 2);
  float* ybuf = (float*)alloc((size_t)T_ * M_ * 4);
  u16* gbuf = (u16*)alloc((size_t)2 * T_ * DFF_ * 2);
  float* topw = (float*)alloc((size_t)T_ * 2 * 4);
  int* topi = (int*)alloc((size_t)T_ * 2 * 4);
  int* cnt = (int*)alloc(64 * 4);
  int* fill = cnt + 8;
  int* off = cnt + 16;
  int* tok_of = (int*)alloc((size_t)2 * T_ * 4);
  int* slot_of = (int*)alloc((size_t)T_ * 2 * 4);
  float* contrib = (float*)qkvb16;   // aliases qkv+ctx (dead after o-proj)

  // 1) weight casts
  {
    auto cast = [&](const float* s, u16* d, size_t n) {
      int n4 = (int)(n / 4);
      int grid = (n4 + 255) / 256;
      if (grid > 4096) grid = 4096;
      hipLaunchKernelGGL(cast_bf16_kernel, dim3(grid), dim3(256), 0, stream, s, d, n4);
    };
    cast(qkvw, wqb, (size_t)QKVN * M_);
    cast(ow, wob, (size_t)M_ * M_);
    cast(w1, w1b, (size_t)E_ * DFF_ * M_);
    cast(w2, w2b, (size_t)E_ * M_ * DFF_);
    cast(w3, w3b, (size_t)E_ * DFF_ * M_);
  }

  // 2) LN1 -> h (bf16)
  hipLaunchKernelGGL(ln_kernel, dim3(T_), dim3(256), 0, stream, x, ln1g, ln1b, hbuf);

  // 3) QKV GEMM
  hipLaunchKernelGGL((gemm_bt_kernel<0>), dim3(T_ / 128, QKVN / 128, 1), dim3(256), 0, stream,
                     hbuf, M_, wqb, 0L, M_, M_, qkvb, (const float*)nullptr, 0,
                     (void*)qkvb16, QKVN, (const int*)nullptr, (const int*)nullptr, T_);

  // 4) attention -> ctx
  hipLaunchKernelGGL(attn_kernel, dim3(S_ / 64, B_ * H_), dim3(256), 0, stream, qkvb16, ctx);

  // 5) y = x + ctx @ ow^T + ob
  hipLaunchKernelGGL((gemm_bt_kernel<1>), dim3(T_ / 128, M_ / 128, 1), dim3(256), 0, stream,
                     ctx, M_, wob, 0L, M_, M_, ob, x, M_,
                     (void*)ybuf, M_, (const int*)nullptr, (const int*)nullptr, T_);

  // 6) LN2 -> h2 (bf16, for expert GEMMs)
  hipLaunchKernelGGL(ln_kernel, dim3(T_), dim3(256), 0, stream, ybuf, ln2g, ln2b, hbuf);

  // 7) routing from fp32 y (fused LN2, double accum)
  hipLaunchKernelGGL(route_kernel, dim3(T_ / 4), dim3(256), 0, stream, ybuf, ln2g, ln2b,
                     gatew, topw, topi);
  hipLaunchKernelGGL(zero_cnt_kernel, dim3(1), dim3(64), 0, stream, cnt);
  hipLaunchKernelGGL(count_kernel, dim3(T_ / 256), dim3(256), 0, stream, topi, cnt);
  hipLaunchKernelGGL(scan_kernel, dim3(1), dim3(64), 0, stream, cnt, off);
  hipLaunchKernelGGL(assign_kernel, dim3(T_ / 256), dim3(256), 0, stream, topi, off, fill,
                     tok_of, slot_of);

  // 8) fused w1/w3 + SwiGLU -> g
  hipLaunchKernelGGL(gemm_moe13_kernel, dim3(T_ / 128, DFF_ / 128, E_), dim3(256), 0, stream,
                     hbuf, w1b, w3b, off, cnt, tok_of, gbuf);

  // 9) w2 GEMM -> contrib
  hipLaunchKernelGGL((gemm_bt_kernel<2>), dim3(T_ / 128, M_ / 128, E_), dim3(256), 0, stream,
                     gbuf, DFF_, w2b, (long)M_ * DFF_, DFF_, DFF_,
                     (const float*)nullptr, (const float*)nullptr, 0,
                     (void*)contrib, M_, off, cnt, 0);

  // 10) combine
  hipLaunchKernelGGL(combine_kernel, dim3(T_), dim3(256), 0, stream, ybuf, contrib, topw,
                     slot_of, out);
}

// Round 3
// 1284.569 us; speedup vs baseline: 1.2955x; 1.2955x over previous
//
#include <hip/hip_runtime.h>
#include <cstdint>
#include <cstddef>

typedef unsigned short u16;
typedef short short8 __attribute__((ext_vector_type(8)));
typedef float floatx4 __attribute__((ext_vector_type(4)));

#define DEVI __device__ __forceinline__

static constexpr int B_ = 2, S_ = 2048, M_ = 1024, H_ = 16, E_ = 8, DFF_ = 4096;
static constexpr int T_ = B_ * S_;          // 4096 tokens
static constexpr int QKVN = 3 * M_;         // 3072

// ---------- scalar bf16 helpers ----------
DEVI float bf2f(u16 u) { union { unsigned u; float f; } v; v.u = ((unsigned)u) << 16; return v.f; }
DEVI u16 f2bf(float f) {
  union { float f; unsigned u; } v; v.f = f;
  unsigned r = (v.u + 0x7FFF + ((v.u >> 16) & 1)) >> 16;   // RNE
  return (u16)r;
}

// ---------- async global->LDS 16B ----------
DEVI void gload_lds16(const void* g, void* l) {
  __builtin_amdgcn_global_load_lds(
      (const __attribute__((address_space(1))) unsigned int*)(uintptr_t)g,
      (__attribute__((address_space(3))) unsigned int*)(unsigned int)(uintptr_t)l,
      16, 0, 0);
}

// ---------- XCD-aware remap: pin all blocks sharing a weight col-slab
// (same wy, wz) to one XCD. Assumes xcd = linear_id % 8 (perf heuristic
// only; correctness never depends on it). For fixed (wy,wz), linear ids
// differ by gy which is a multiple of 8 for all our grids. ----------
DEVI void xcd_remap(int gx, int gy, int& wx, int& wy, int& wz) {
  int L = blockIdx.x + gx * (blockIdx.y + gy * blockIdx.z);
  int pg = gx * gy;
  wz = L / pg;
  int r = L - wz * pg;
  wy = r % gy;
  wx = r / gy;
}

// ---------- fp32 -> bf16 bulk cast ----------
__global__ __launch_bounds__(256) void cast_bf16_kernel(const float* __restrict__ src,
                                                        u16* __restrict__ dst, int n4) {
  int i = blockIdx.x * 256 + threadIdx.x;
  int stride = gridDim.x * 256;
  for (; i < n4; i += stride) {
    float4 v = ((const float4*)src)[i];
    ushort4 o;
    o.x = f2bf(v.x); o.y = f2bf(v.y); o.z = f2bf(v.z); o.w = f2bf(v.w);
    ((ushort4*)dst)[i] = o;
  }
}

// ---------- LayerNorm ----------
__global__ __launch_bounds__(256) void ln_kernel(const float* __restrict__ x,
                                                 const float* __restrict__ g,
                                                 const float* __restrict__ b,
                                                 u16* __restrict__ out) {
  int t = blockIdx.x;
  int tid = threadIdx.x;
  float4 v = ((const float4*)(x + (size_t)t * M_))[tid];
  float s = v.x + v.y + v.z + v.w;
  float sq = v.x * v.x + v.y * v.y + v.z * v.z + v.w * v.w;
  for (int m = 1; m < 64; m <<= 1) { s += __shfl_xor(s, m); sq += __shfl_xor(sq, m); }
  __shared__ float ps[4], pq[4];
  int w = tid >> 6;
  if ((tid & 63) == 0) { ps[w] = s; pq[w] = sq; }
  __syncthreads();
  s = ps[0] + ps[1] + ps[2] + ps[3];
  sq = pq[0] + pq[1] + pq[2] + pq[3];
  float mean = s * (1.f / M_);
  float var = sq * (1.f / M_) - mean * mean;
  float rstd = rsqrtf(var + 1e-5f);
  int c = tid * 4;
  ushort4 o;
  o.x = f2bf((v.x - mean) * rstd * g[c + 0] + b[c + 0]);
  o.y = f2bf((v.y - mean) * rstd * g[c + 1] + b[c + 1]);
  o.z = f2bf((v.z - mean) * rstd * g[c + 2] + b[c + 2]);
  o.w = f2bf((v.w - mean) * rstd * g[c + 3] + b[c + 3]);
  ((ushort4*)(out + (size_t)t * M_))[tid] = o;
}

// =================================================================
// Core GEMM: C[rows x N] = A[rows x K](bf16) @ W[N x K]^T(bf16)
// EPI: 0 = bf16 out + bias; 1 = f32 out + bias + residual; 2 = f32 out.
// SWZ: 1 = XCD-pin weight col-slabs (weights fetched once per slab).
// =================================================================
template <int EPI, int SWZ>
__global__ __launch_bounds__(256, 2) void gemm_bt_kernel(
    const u16* __restrict__ A, int lda,
    const u16* __restrict__ Wb, long wstride, int ldw, int K,
    const float* __restrict__ bias, const float* __restrict__ resid, int ldr,
    void* __restrict__ Cout, int ldc,
    const int* __restrict__ d_off, const int* __restrict__ d_cnt, int rowsDefault) {
  int bx, by, bz;
  if (SWZ) {
    xcd_remap(gridDim.x, gridDim.y, bx, by, bz);
  } else {
    bx = blockIdx.x; by = blockIdx.y; bz = blockIdx.z;
  }
  const u16* W = Wb + (long)bz * wstride;
  int rowBase = 0, rows = rowsDefault;
  if (d_off) { rowBase = d_off[bz]; rows = d_cnt[bz]; }
  int mt0 = bx * 128;
  if (mt0 >= rows) return;
  int col0 = by * 128;

  __shared__ u16 As[128 * 32];
  __shared__ u16 Bs[128 * 32];
  char* AsB = (char*)As;
  char* BsB = (char*)Bs;

  int tid = threadIdx.x;
  int lane = tid & 63, wave = tid >> 6;
  int quad = lane >> 4, nlo = lane & 15;
  int wr = wave >> 1, wc = wave & 1;

  int r0 = tid >> 2, r1 = (tid + 256) >> 2;
  int slot = tid & 3;
  int kc0 = slot ^ ((r0 >> 1) & 3);
  int kc1 = slot ^ ((r1 >> 1) & 3);
  int ar0 = rowBase + mt0 + r0; if (ar0 >= rowBase + rows) ar0 = rowBase;
  int ar1 = rowBase + mt0 + r1; if (ar1 >= rowBase + rows) ar1 = rowBase;
  const u16* Ap0 = A + (size_t)ar0 * lda + kc0 * 8;
  const u16* Ap1 = A + (size_t)ar1 * lda + kc1 * 8;
  const u16* Wp0 = W + (size_t)(col0 + r0) * ldw + kc0 * 8;
  const u16* Wp1 = W + (size_t)(col0 + r1) * ldw + kc1 * 8;
  char* a_dst0 = AsB + tid * 16;
  char* a_dst1 = AsB + (tid + 256) * 16;
  char* b_dst0 = BsB + tid * 16;
  char* b_dst1 = BsB + (tid + 256) * 16;

  floatx4 acc[4][4];
#pragma unroll
  for (int i = 0; i < 4; i++)
#pragma unroll
    for (int j = 0; j < 4; j++) acc[i][j] = (floatx4)0.f;

  for (int k0 = 0; k0 < K; k0 += 32) {
    __syncthreads();
    gload_lds16(Ap0 + k0, a_dst0);
    gload_lds16(Ap1 + k0, a_dst1);
    gload_lds16(Wp0 + k0, b_dst0);
    gload_lds16(Wp1 + k0, b_dst1);
    __syncthreads();
    short8 af[4], bfv[4];
#pragma unroll
    for (int mt = 0; mt < 4; mt++) {
      int rr = wr * 64 + mt * 16 + nlo;
      int ch = rr * 4 + (quad ^ ((rr >> 1) & 3));
      af[mt] = *(const short8*)(AsB + ch * 16);
    }
#pragma unroll
    for (int nt = 0; nt < 4; nt++) {
      int rr = wc * 64 + nt * 16 + nlo;
      int ch = rr * 4 + (quad ^ ((rr >> 1) & 3));
      bfv[nt] = *(const short8*)(BsB + ch * 16);
    }
#pragma unroll
    for (int mt = 0; mt < 4; mt++)
#pragma unroll
      for (int nt = 0; nt < 4; nt++)
        acc[mt][nt] = __builtin_amdgcn_mfma_f32_16x16x32_bf16(af[mt], bfv[nt], acc[mt][nt], 0, 0, 0);
  }

#pragma unroll
  for (int mt = 0; mt < 4; mt++) {
#pragma unroll
    for (int r = 0; r < 4; r++) {
      int row = rowBase + mt0 + wr * 64 + mt * 16 + quad * 4 + r;
      if (row >= rowBase + rows) continue;
#pragma unroll
      for (int nt = 0; nt < 4; nt++) {
        int col = col0 + wc * 64 + nt * 16 + nlo;
        float v = acc[mt][nt][r];
        if (EPI == 0) {
          v += bias[col];
          ((u16*)Cout)[(size_t)row * ldc + col] = f2bf(v);
        } else if (EPI == 1) {
          v += bias[col] + resid[(size_t)row * ldr + col];
          ((float*)Cout)[(size_t)row * ldc + col] = v;
        } else {
          ((float*)Cout)[(size_t)row * ldc + col] = v;
        }
      }
    }
  }
}

// =================================================================
// Fused MoE w1/w3 GEMM with token gather + SwiGLU epilogue -> g (bf16)
// =================================================================
__global__ __launch_bounds__(256, 2) void gemm_moe13_kernel(
    const u16* __restrict__ h2, const u16* __restrict__ w1b, const u16* __restrict__ w3b,
    const int* __restrict__ d_off, const int* __restrict__ d_cnt,
    const int* __restrict__ tok_of, u16* __restrict__ g) {
  int bx, by, bz;
  xcd_remap(gridDim.x, gridDim.y, bx, by, bz);
  int e = bz;
  int off = d_off[e], cnt = d_cnt[e];
  int mt0 = bx * 128;
  if (mt0 >= cnt) return;
  int col0 = by * 128;
  const u16* W1 = w1b + (size_t)e * DFF_ * M_;
  const u16* W3 = w3b + (size_t)e * DFF_ * M_;

  __shared__ u16 As[128 * 32];
  __shared__ u16 B1s[128 * 32];
  __shared__ u16 B3s[128 * 32];
  char* AsB = (char*)As;
  char* B1B = (char*)B1s;
  char* B3B = (char*)B3s;

  int tid = threadIdx.x;
  int lane = tid & 63, wave = tid >> 6;
  int quad = lane >> 4, nlo = lane & 15;
  int wr = wave >> 1, wc = wave & 1;

  int r0 = tid >> 2, r1 = (tid + 256) >> 2;
  int slot = tid & 3;
  int kc0 = slot ^ ((r0 >> 1) & 3);
  int kc1 = slot ^ ((r1 >> 1) & 3);
  int a0 = off + mt0 + r0; if (a0 >= off + cnt) a0 = off;
  int a1 = off + mt0 + r1; if (a1 >= off + cnt) a1 = off;
  int tok0 = tok_of[a0], tok1 = tok_of[a1];
  const u16* Ap0 = h2 + (size_t)tok0 * M_ + kc0 * 8;
  const u16* Ap1 = h2 + (size_t)tok1 * M_ + kc1 * 8;
  const u16* W1p0 = W1 + (size_t)(col0 + r0) * M_ + kc0 * 8;
  const u16* W1p1 = W1 + (size_t)(col0 + r1) * M_ + kc1 * 8;
  const u16* W3p0 = W3 + (size_t)(col0 + r0) * M_ + kc0 * 8;
  const u16* W3p1 = W3 + (size_t)(col0 + r1) * M_ + kc1 * 8;

  floatx4 acc1[4][4], acc3[4][4];
#pragma unroll
  for (int i = 0; i < 4; i++)
#pragma unroll
    for (int j = 0; j < 4; j++) { acc1[i][j] = (floatx4)0.f; acc3[i][j] = (floatx4)0.f; }

  for (int k0 = 0; k0 < M_; k0 += 32) {
    __syncthreads();
    gload_lds16(Ap0 + k0, AsB + tid * 16);
    gload_lds16(Ap1 + k0, AsB + (tid + 256) * 16);
    gload_lds16(W1p0 + k0, B1B + tid * 16);
    gload_lds16(W1p1 + k0, B1B + (tid + 256) * 16);
    gload_lds16(W3p0 + k0, B3B + tid * 16);
    gload_lds16(W3p1 + k0, B3B + (tid + 256) * 16);
    __syncthreads();
    short8 af[4], b1f[4], b3f[4];
#pragma unroll
    for (int mt = 0; mt < 4; mt++) {
      int rr = wr * 64 + mt * 16 + nlo;
      int ch = rr * 4 + (quad ^ ((rr >> 1) & 3));
      af[mt] = *(const short8*)(AsB + ch * 16);
    }
#pragma unroll
    for (int nt = 0; nt < 4; nt++) {
      int rr = wc * 64 + nt * 16 + nlo;
      int ch = rr * 4 + (quad ^ ((rr >> 1) & 3));
      b1f[nt] = *(const short8*)(B1B + ch * 16);
      b3f[nt] = *(const short8*)(B3B + ch * 16);
    }
#pragma unroll
    for (int mt = 0; mt < 4; mt++)
#pragma unroll
      for (int nt = 0; nt < 4; nt++) {
        acc1[mt][nt] = __builtin_amdgcn_mfma_f32_16x16x32_bf16(af[mt], b1f[nt], acc1[mt][nt], 0, 0, 0);
        acc3[mt][nt] = __builtin_amdgcn_mfma_f32_16x16x32_bf16(af[mt], b3f[nt], acc3[mt][nt], 0, 0, 0);
      }
  }

#pragma unroll
  for (int mt = 0; mt < 4; mt++) {
#pragma unroll
    for (int r = 0; r < 4; r++) {
      int a = off + mt0 + wr * 64 + mt * 16 + quad * 4 + r;
      if (a >= off + cnt) continue;
#pragma unroll
      for (int nt = 0; nt < 4; nt++) {
        int col = col0 + wc * 64 + nt * 16 + nlo;
        float x1 = acc1[mt][nt][r];
        float x3 = acc3[mt][nt][r];
        float sil = x1 / (1.f + __expf(-x1));
        g[(size_t)a * DFF_ + col] = f2bf(sil * x3);
      }
    }
  }
}

// =================================================================
// Flash attention
// =================================================================
__global__ __launch_bounds__(256, 4) void attn_kernel(const u16* __restrict__ qkv,
                                                      u16* __restrict__ ctx) {
  int qblk = blockIdx.x;
  int bh = blockIdx.y;
  int b = bh >> 4, h = bh & 15;
  int tid = threadIdx.x;
  int wave = tid >> 6, lane = tid & 63;
  int quad = lane >> 4, nlo = lane & 15;
  int qw = qblk * 64 + wave * 16;

  __shared__ u16 Kl[32 * 72];
  __shared__ u16 Vl[64 * 56];
  __shared__ u16 Pl[4 * 16 * 56];
  u16* Pw = Pl + wave * 16 * 56;

  const size_t rs = 3072;
  const u16* base = qkv + (size_t)b * S_ * rs;

  short8 aq[2];
  {
    int qrow = qw + nlo;
    const u16* qp = base + (size_t)qrow * rs + h * 64 + quad * 8;
    aq[0] = *(const short8*)(qp);
    aq[1] = *(const short8*)(qp + 32);
  }

  floatx4 oc[4];
#pragma unroll
  for (int i = 0; i < 4; i++) oc[i] = (floatx4)0.f;
  float m_i[4], l_i[4];
#pragma unroll
  for (int r = 0; r < 4; r++) { m_i[r] = -1e30f; l_i[r] = 0.f; }

  int nkt = (qblk * 64) / 32 + 2;
  for (int kt = 0; kt < nkt; kt++) {
    int kbase = kt * 32;
    __syncthreads();
    {
      int key = tid >> 3, d0 = (tid & 7) * 8;
      const u16* kp = base + (size_t)(kbase + key) * rs + 1024 + h * 64 + d0;
      short8 kv = *(const short8*)kp;
      *(short8*)(Kl + key * 72 + d0) = kv;
      union { short8 v; u16 u[8]; } vv;
      vv.v = *(const short8*)(kp + 1024);
#pragma unroll
      for (int i = 0; i < 8; i++) Vl[(d0 + i) * 56 + key] = vv.u[i];
    }
    __syncthreads();
    if (kbase > qw + 15) continue;

    floatx4 sc[2];
    sc[0] = (floatx4)0.f; sc[1] = (floatx4)0.f;
#pragma unroll
    for (int nt = 0; nt < 2; nt++)
#pragma unroll
      for (int kd = 0; kd < 2; kd++) {
        short8 bk = *(const short8*)(Kl + (nt * 16 + nlo) * 72 + kd * 32 + quad * 8);
        sc[nt] = __builtin_amdgcn_mfma_f32_16x16x32_bf16(aq[kd], bk, sc[nt], 0, 0, 0);
      }

    float p[2][4], alpha[4];
#pragma unroll
    for (int r = 0; r < 4; r++) {
      int qrow = qw + quad * 4 + r;
      float s0v = sc[0][r]; if (kbase + nlo > qrow) s0v = -1e30f;
      float s1v = sc[1][r]; if (kbase + 16 + nlo > qrow) s1v = -1e30f;
      float mx = fmaxf(s0v, s1v);
#pragma unroll
      for (int m = 1; m < 16; m <<= 1) mx = fmaxf(mx, __shfl_xor(mx, m));
      float mnew = fmaxf(m_i[r], mx);
      alpha[r] = __expf(m_i[r] - mnew);
      float p0 = __expf(s0v - mnew), p1 = __expf(s1v - mnew);
      float rsum = p0 + p1;
#pragma unroll
      for (int m = 1; m < 16; m <<= 1) rsum += __shfl_xor(rsum, m);
      l_i[r] = l_i[r] * alpha[r] + rsum;
      m_i[r] = mnew;
      p[0][r] = p0; p[1][r] = p1;
    }
#pragma unroll
    for (int d = 0; d < 4; d++)
#pragma unroll
      for (int r = 0; r < 4; r++) oc[d][r] *= alpha[r];
#pragma unroll
    for (int nt = 0; nt < 2; nt++)
#pragma unroll
      for (int r = 0; r < 4; r++)
        Pw[(quad * 4 + r) * 56 + nt * 16 + nlo] = f2bf(p[nt][r]);

    short8 ap = *(const short8*)(Pw + nlo * 56 + quad * 8);
#pragma unroll
    for (int d = 0; d < 4; d++) {
      short8 bv = *(const short8*)(Vl + (d * 16 + nlo) * 56 + quad * 8);
      oc[d] = __builtin_amdgcn_mfma_f32_16x16x32_bf16(ap, bv, oc[d], 0, 0, 0);
    }
  }

  float inv[4];
#pragma unroll
  for (int r = 0; r < 4; r++) inv[r] = 1.f / l_i[r];
#pragma unroll
  for (int d = 0; d < 4; d++)
#pragma unroll
    for (int r = 0; r < 4; r++) {
      int qrow = qw + quad * 4 + r;
      ctx[((size_t)(b * S_ + qrow)) * M_ + h * 64 + d * 16 + nlo] = f2bf(oc[d][r] * inv[r]);
    }
}

// ---------- MoE routing: fp32 LN2 fused + double-accum gate logits ----------
__global__ __launch_bounds__(256) void route_kernel(const float* __restrict__ y,
                                                    const float* __restrict__ g,
                                                    const float* __restrict__ b,
                                                    const float* __restrict__ gw,
                                                    float* __restrict__ topw,
                                                    int* __restrict__ topi) {
  int wave = threadIdx.x >> 6, lane = threadIdx.x & 63;
  int t = blockIdx.x * 4 + wave;
  const float* yr = y + (size_t)t * M_;
  float4 v[4];
  float s = 0.f, sq = 0.f;
#pragma unroll
  for (int i = 0; i < 4; i++) {
    v[i] = ((const float4*)yr)[lane + i * 64];
    s += v[i].x + v[i].y + v[i].z + v[i].w;
    sq += v[i].x * v[i].x + v[i].y * v[i].y + v[i].z * v[i].z + v[i].w * v[i].w;
  }
#pragma unroll
  for (int m = 1; m < 64; m <<= 1) { s += __shfl_xor(s, m); sq += __shfl_xor(sq, m); }
  float mean = s * (1.f / M_);
  float var = sq * (1.f / M_) - mean * mean;
  float rstd = rsqrtf(var + 1e-5f);

  double acc[8];
#pragma unroll
  for (int e = 0; e < 8; e++) acc[e] = 0.0;
#pragma unroll
  for (int i = 0; i < 4; i++) {
    int d = (lane + i * 64) * 4;
    float4 gg = ((const float4*)(g + d))[0];
    float4 bb = ((const float4*)(b + d))[0];
    float h0 = (v[i].x - mean) * rstd * gg.x + bb.x;
    float h1 = (v[i].y - mean) * rstd * gg.y + bb.y;
    float h2v = (v[i].z - mean) * rstd * gg.z + bb.z;
    float h3 = (v[i].w - mean) * rstd * gg.w + bb.w;
#pragma unroll
    for (int e = 0; e < 8; e++) {
      float4 w4 = ((const float4*)(gw + (size_t)e * M_ + d))[0];
      acc[e] += (double)h0 * w4.x + (double)h1 * w4.y + (double)h2v * w4.z + (double)h3 * w4.w;
    }
  }
#pragma unroll
  for (int e = 0; e < 8; e++)
#pragma unroll
    for (int m = 1; m < 64; m <<= 1) acc[e] += __shfl_xor(acc[e], m);
  if (lane == 0) {
    int i1 = 0; double v1 = acc[0];
#pragma unroll
    for (int e = 1; e < 8; e++) if (acc[e] > v1) { v1 = acc[e]; i1 = e; }
    int i2 = -1; double v2 = -1e300;
#pragma unroll
    for (int e = 0; e < 8; e++) if (e != i1 && acc[e] > v2) { v2 = acc[e]; i2 = e; }
    double z = exp(v2 - v1);
    topi[t * 2] = i1; topi[t * 2 + 1] = i2;
    topw[t * 2] = (float)(1.0 / (1.0 + z));
    topw[t * 2 + 1] = (float)(z / (1.0 + z));
  }
}

__global__ void zero_cnt_kernel(int* cnt) { if (threadIdx.x < 16) cnt[threadIdx.x] = 0; }

__global__ __launch_bounds__(256) void count_kernel(const int* __restrict__ topi, int* cnt) {
  int t = blockIdx.x * 256 + threadIdx.x;
  if (t < T_) {
    atomicAdd(&cnt[topi[2 * t]], 1);
    atomicAdd(&cnt[topi[2 * t + 1]], 1);
  }
}

__global__ void scan_kernel(const int* __restrict__ cnt, int* off) {
  if (threadIdx.x == 0) {
    int s = 0;
    for (int e = 0; e < E_; e++) { off[e] = s; s += cnt[e]; }
  }
}

__global__ __launch_bounds__(256) void assign_kernel(const int* __restrict__ topi,
                                                     const int* __restrict__ off, int* fill,
                                                     int* __restrict__ tok_of,
                                                     int* __restrict__ slot_of) {
  int t = blockIdx.x * 256 + threadIdx.x;
  if (t < T_) {
#pragma unroll
    for (int j = 0; j < 2; j++) {
      int e = topi[2 * t + j];
      int pos = atomicAdd(&fill[e], 1);
      int a = off[e] + pos;
      tok_of[a] = t;
      slot_of[2 * t + j] = a;
    }
  }
}

// ---------- final combine ----------
__global__ __launch_bounds__(256) void combine_kernel(const float* __restrict__ y,
                                                      const float* __restrict__ contrib,
                                                      const float* __restrict__ topw,
                                                      const int* __restrict__ slot_of,
                                                      float* __restrict__ out) {
  int t = blockIdx.x;
  int c = threadIdx.x;
  int s0 = slot_of[2 * t], s1 = slot_of[2 * t + 1];
  float w0 = topw[2 * t], w1 = topw[2 * t + 1];
  float4 a = ((const float4*)(y + (size_t)t * M_))[c];
  float4 p = ((const float4*)(contrib + (size_t)s0 * M_))[c];
  float4 q = ((const float4*)(contrib + (size_t)s1 * M_))[c];
  float4 o;
  o.x = a.x + w0 * p.x + w1 * q.x;
  o.y = a.y + w0 * p.y + w1 * q.y;
  o.z = a.z + w0 * p.z + w1 * q.z;
  o.w = a.w + w0 * p.w + w1 * q.w;
  ((float4*)(out + (size_t)t * M_))[c] = o;
}

// =================================================================
extern "C" void kernel_launch(void* const* d_in, const int* in_sizes, int n_in,
                              void* d_out, int out_size, void* d_ws, size_t ws_size,
                              hipStream_t stream) {
  const float* x = (const float*)d_in[0];
  const float* ln1g = (const float*)d_in[1];
  const float* ln1b = (const float*)d_in[2];
  const float* qkvw = (const float*)d_in[3];
  const float* qkvb = (const float*)d_in[4];
  const float* ow = (const float*)d_in[5];
  const float* ob = (const float*)d_in[6];
  const float* ln2g = (const float*)d_in[7];
  const float* ln2b = (const float*)d_in[8];
  const float* gatew = (const float*)d_in[9];
  const float* w1 = (const float*)d_in[10];
  const float* w2 = (const float*)d_in[11];
  const float* w3 = (const float*)d_in[12];
  float* out = (float*)d_out;

  char* p = (char*)d_ws;
  auto alloc = [&](size_t bytes) {
    char* r = p;
    p += (bytes + 255) & ~(size_t)255;
    return r;
  };
  u16* wqb = (u16*)alloc((size_t)QKVN * M_ * 2);
  u16* wob = (u16*)alloc((size_t)M_ * M_ * 2);
  u16* w1b = (u16*)alloc((size_t)E_ * DFF_ * M_ * 2);
  u16* w2b = (u16*)alloc((size_t)E_ * M_ * DFF_ * 2);
  u16* w3b = (u16*)alloc((size_t)E_ * DFF_ * M_ * 2);
  u16* hbuf = (u16*)alloc((size_t)T_ * M_ * 2);
  u16* qkvb16 = (u16*)alloc((size_t)T_ * QKVN * 2);
  u16* ctx = (u16*)alloc((size_t)T_ * M_ * 2);
  float* ybuf = (float*)alloc((size_t)T_ * M_ * 4);
  u16* gbuf = (u16*)alloc((size_t)2 * T_ * DFF_ * 2);
  float* topw = (float*)alloc((size_t)T_ * 2 * 4);
  int* topi = (int*)alloc((size_t)T_ * 2 * 4);
  int* cnt = (int*)alloc(64 * 4);
  int* fill = cnt + 8;
  int* off = cnt + 16;
  int* tok_of = (int*)alloc((size_t)2 * T_ * 4);
  int* slot_of = (int*)alloc((size_t)T_ * 2 * 4);
  float* contrib = (float*)qkvb16;   // aliases qkv+ctx (dead after o-proj)

  // 1) weight casts
  {
    auto cast = [&](const float* s, u16* d, size_t n) {
      int n4 = (int)(n / 4);
      int grid = (n4 + 255) / 256;
      if (grid > 4096) grid = 4096;
      hipLaunchKernelGGL(cast_bf16_kernel, dim3(grid), dim3(256), 0, stream, s, d, n4);
    };
    cast(qkvw, wqb, (size_t)QKVN * M_);
    cast(ow, wob, (size_t)M_ * M_);
    cast(w1, w1b, (size_t)E_ * DFF_ * M_);
    cast(w2, w2b, (size_t)E_ * M_ * DFF_);
    cast(w3, w3b, (size_t)E_ * DFF_ * M_);
  }

  // 2) LN1 -> h (bf16)
  hipLaunchKernelGGL(ln_kernel, dim3(T_), dim3(256), 0, stream, x, ln1g, ln1b, hbuf);

  // 3) QKV GEMM (XCD-swizzled)
  hipLaunchKernelGGL((gemm_bt_kernel<0, 1>), dim3(T_ / 128, QKVN / 128, 1), dim3(256), 0, stream,
                     hbuf, M_, wqb, 0L, M_, M_, qkvb, (const float*)nullptr, 0,
                     (void*)qkvb16, QKVN, (const int*)nullptr, (const int*)nullptr, T_);

  // 4) attention -> ctx
  hipLaunchKernelGGL(attn_kernel, dim3(S_ / 64, B_ * H_), dim3(256), 0, stream, qkvb16, ctx);

  // 5) y = x + ctx @ ow^T + ob (XCD-swizzled)
  hipLaunchKernelGGL((gemm_bt_kernel<1, 1>), dim3(T_ / 128, M_ / 128, 1), dim3(256), 0, stream,
                     ctx, M_, wob, 0L, M_, M_, ob, x, M_,
                     (void*)ybuf, M_, (const int*)nullptr, (const int*)nullptr, T_);

  // 6) LN2 -> h2 (bf16, for expert GEMMs)
  hipLaunchKernelGGL(ln_kernel, dim3(T_), dim3(256), 0, stream, ybuf, ln2g, ln2b, hbuf);

  // 7) routing from fp32 y (fused LN2, double accum)
  hipLaunchKernelGGL(route_kernel, dim3(T_ / 4), dim3(256), 0, stream, ybuf, ln2g, ln2b,
                     gatew, topw, topi);
  hipLaunchKernelGGL(zero_cnt_kernel, dim3(1), dim3(64), 0, stream, cnt);
  hipLaunchKernelGGL(count_kernel, dim3(T_ / 256), dim3(256), 0, stream, topi, cnt);
  hipLaunchKernelGGL(scan_kernel, dim3(1), dim3(64), 0, stream, cnt, off);
  hipLaunchKernelGGL(assign_kernel, dim3(T_ / 256), dim3(256), 0, stream, topi, off, fill,
                     tok_of, slot_of);

  // 8) fused w1/w3 + SwiGLU -> g (XCD-swizzled)
  hipLaunchKernelGGL(gemm_moe13_kernel, dim3(T_ / 128, DFF_ / 128, E_), dim3(256), 0, stream,
                     hbuf, w1b, w3b, off, cnt, tok_of, gbuf);

  // 9) w2 GEMM -> contrib (natural order: A/W volumes symmetric, isolate variable)
  hipLaunchKernelGGL((gemm_bt_kernel<2, 0>), dim3(T_ / 128, M_ / 128, E_), dim3(256), 0, stream,
                     gbuf, DFF_, w2b, (long)M_ * DFF_, DFF_, DFF_,
                     (const float*)nullptr, (const float*)nullptr, 0,
                     (void*)contrib, M_, off, cnt, 0);

  // 10) combine
  hipLaunchKernelGGL(combine_kernel, dim3(T_), dim3(256), 0, stream, ybuf, contrib, topw,
                     slot_of, out);
}